// Round 14
// baseline (155.782 us; speedup 1.0000x reference)
//
#include <hip/hip_runtime.h>
#include <hip/hip_bf16.h>

// Retention: out = (tril(alpha^(i-j)) * (QK^T/sqrt(d))) @ V, qkv = x@W + b
// Decay folded into operands: Q' = q*alpha^i/sqrt(d), K' = k*alpha^(-j)
// All GEMMs: r5 core (128x128, BK=64 dbuf, 8 waves of 32x64, 64KB LDS ->
// 2 blocks/CU, counted vmcnt gates, 0-conflict swizzle slot = chunk^(row&7)).
// r14: convert_x folded into qkv A-staging (f32 loads -> v_cvt_pk_bf16_f32 ->
// swizzled ds_write_b128, issued one K-tile early; B stays global_load_lds).
// prep = transpose_w only. Queue arithmetic: ISSUE(t) = [A:4, B:2] in order;
// steady state holds 2 tiles (12 ops); vmcnt(6) completes the older tile.

#define SEQ   1024
#define DIM   768
#define ND3   2304

typedef __attribute__((ext_vector_type(8))) short bf16x8;
typedef __attribute__((ext_vector_type(4))) float f32x4;

#define L2A     (-0.014499569695115089f)   // log2(0.99)
#define RSQRTD  (0.03608439182435161f)     // 1/sqrt(768)

__device__ __forceinline__ unsigned short f2bf(float x) {
  union { float f; unsigned u; } v; v.f = x;
  unsigned r = v.u + 0x7FFFu + ((v.u >> 16) & 1u);
  return (unsigned short)(r >> 16);
}

__device__ __forceinline__ void gload16(const void* g, void* l) {
  __builtin_amdgcn_global_load_lds(
      (const __attribute__((address_space(1))) void*)g,
      (__attribute__((address_space(3))) void*)l, 16, 0, 0);
}

// ======================= r5 core (BK=64 dbuf, proven) for score/pv =========
__device__ __forceinline__ void gemm_core(
    const unsigned short* gA, const unsigned short* gA2,
    const unsigned short* gB, const unsigned short* gB2,
    char* lsA, char* lsB, int nt, int wid, int lane, f32x4 acc[2][4]) {
  int lr = lane & 15, lg = lane >> 4;
  int wm = wid >> 1, wn = wid & 1;
  int rdA = (wm * 32 + lr) * 128 + ((lg ^ (lr & 7)) << 4);
  int rdB = (wn * 64 + lr) * 128 + ((lg ^ (lr & 7)) << 4);
  int wo = wid * 2048;

#define STAGE(t, par) do {                                                    \
    int lo_ = ((par) << 14) + wo;                                             \
    gload16(gA  + (size_t)(t) * 64, lsA + lo_);                               \
    gload16(gA2 + (size_t)(t) * 64, lsA + lo_ + 1024);                        \
    gload16(gB  + (size_t)(t) * 64, lsB + lo_);                               \
    gload16(gB2 + (size_t)(t) * 64, lsB + lo_ + 1024);                        \
  } while (0)

  STAGE(0, 0);
  STAGE(1, 1);
  asm volatile("s_waitcnt vmcnt(4)" ::: "memory");
  __builtin_amdgcn_s_barrier();
  asm volatile("" ::: "memory");

  for (int t = 0; t < nt; ++t) {
    int pbase = (t & 1) << 14;
    bf16x8 aF[2][2], bF[2][4];
#pragma unroll
    for (int kh = 0; kh < 2; ++kh) {
#pragma unroll
      for (int f = 0; f < 2; ++f)
        aF[kh][f] = *(const bf16x8*)(lsA + pbase + ((rdA + f * 2048) ^ (kh << 6)));
#pragma unroll
      for (int n = 0; n < 4; ++n)
        bF[kh][n] = *(const bf16x8*)(lsB + pbase + ((rdB + n * 2048) ^ (kh << 6)));
    }
    __builtin_amdgcn_s_setprio(1);
#pragma unroll
    for (int kh = 0; kh < 2; ++kh)
#pragma unroll
      for (int f = 0; f < 2; ++f)
#pragma unroll
        for (int n = 0; n < 4; ++n)
          acc[f][n] = __builtin_amdgcn_mfma_f32_16x16x32_bf16(aF[kh][f], bF[kh][n], acc[f][n], 0, 0, 0);
    __builtin_amdgcn_s_setprio(0);

    if (t == nt - 1) break;
    __builtin_amdgcn_s_barrier();
    asm volatile("" ::: "memory");
    if (t + 2 < nt) {
      STAGE(t + 2, t & 1);
      asm volatile("s_waitcnt vmcnt(4)" ::: "memory");
    } else {
      asm volatile("s_waitcnt vmcnt(0)" ::: "memory");
    }
    __builtin_amdgcn_s_barrier();
    asm volatile("" ::: "memory");
  }
#undef STAGE
}

// ---------------- transpose W: W[768][2304] f32 -> Wt[2304][768] bf16
__global__ void transpose_w(const float* __restrict__ W, unsigned short* __restrict__ Wt) {
  __shared__ float tile[64][65];
  int n0 = (blockIdx.x % 36) * 64;
  int k0 = (blockIdx.x / 36) * 64;
  int tx = threadIdx.x & 63, ty = threadIdx.x >> 6;
#pragma unroll
  for (int p = 0; p < 16; ++p) {
    int k = ty + p * 4;
    tile[k][tx] = W[(size_t)(k0 + k) * ND3 + n0 + tx];
  }
  __syncthreads();
#pragma unroll
  for (int p = 0; p < 16; ++p) {
    int n = ty + p * 4;
    Wt[(size_t)(n0 + n) * DIM + k0 + tx] = f2bf(tile[tx][n]);
  }
}

// ---------------- QKV: x[16384][768] f32 @ Wt^T -> Q',K',Vt. grid 2304.
// A staged via reg (f32 load -> cvt_pk -> swizzled ds_write), B via gload_lds.
__global__ void __launch_bounds__(512, 4) qkv_g(
    const float* __restrict__ x, const unsigned short* __restrict__ Wt,
    const float* __restrict__ bias,
    unsigned short* __restrict__ Qs, unsigned short* __restrict__ Ks,
    unsigned short* __restrict__ Vt) {
  __shared__ __align__(1024) char lsA[32768];
  __shared__ __align__(1024) char lsB[32768];
  int bid = (blockIdx.x & 7) * 288 + (blockIdx.x >> 3);   // bijective XCD swizzle
  int mt = bid / 18, ntb = bid % 18;                      // mt-major (A-tile L2-resident)
  int m0 = mt * 128, n0 = ntb * 128;

  int tid = threadIdx.x, lane = tid & 63, wid = tid >> 6;
  int lr = lane & 15, lg = lane >> 4;
  int wm = wid >> 1, wn = wid & 1;

  // B staging (gload_lds, pre-swizzled source)
  int l8 = lane >> 3, csB = ((lane & 7) ^ l8) << 3;
  const unsigned short* gB  = Wt + (size_t)(n0 + wid * 16 + l8) * DIM + csB;
  const unsigned short* gB2 = gB + (size_t)8 * DIM;
  // A reg-staging: lane covers row wid*16+(lane>>2), 16 consecutive f32 at (lane&3)*16
  const float* gAf = x + (size_t)(m0 + wid * 16 + (lane >> 2)) * DIM + (lane & 3) * 16;
  // A ds_write dests: row's chunks c0=(lane&3)*2, c0+1 at slot c^(row&7)
  int arow = wid * 16 + (lane >> 2);
  int awr0 = arow * 128 + ((((lane & 3) * 2)     ^ (arow & 7)) << 4);
  int awr1 = arow * 128 + ((((lane & 3) * 2 + 1) ^ (arow & 7)) << 4);
  // ds_read offsets (r5 scheme)
  int rdA = (wm * 32 + lr) * 128 + ((lg ^ (lr & 7)) << 4);
  int rdB = (wn * 64 + lr) * 128 + ((lg ^ (lr & 7)) << 4);

  f32x4 acc[2][4] = {};

#define ISSUE(t, f0, f1, f2, f3) do {                                         \
    const float* s_ = gAf + (t) * 64;                                         \
    f0 = *(const float4*)(s_);                                                \
    f1 = *(const float4*)(s_ + 4);                                            \
    f2 = *(const float4*)(s_ + 8);                                            \
    f3 = *(const float4*)(s_ + 12);                                           \
    gload16(gB  + (size_t)(t) * 64, lsB + (((t) & 1) << 14) + wid * 2048);    \
    gload16(gB2 + (size_t)(t) * 64, lsB + (((t) & 1) << 14) + wid * 2048 + 1024);\
  } while (0)
#define CVT8(dst, fa, fb) do {                                                \
    unsigned q0_, q1_, q2_, q3_;                                              \
    asm("v_cvt_pk_bf16_f32 %0, %1, %2" : "=v"(q0_) : "v"(fa.x), "v"(fa.y));   \
    asm("v_cvt_pk_bf16_f32 %0, %1, %2" : "=v"(q1_) : "v"(fa.z), "v"(fa.w));   \
    asm("v_cvt_pk_bf16_f32 %0, %1, %2" : "=v"(q2_) : "v"(fb.x), "v"(fb.y));   \
    asm("v_cvt_pk_bf16_f32 %0, %1, %2" : "=v"(q3_) : "v"(fb.z), "v"(fb.w));   \
    *(uint4*)(dst) = make_uint4(q0_, q1_, q2_, q3_);                          \
  } while (0)
#define WRITE_A(par, f0, f1, f2, f3) do {                                     \
    CVT8(lsA + ((par) << 14) + awr0, f0, f1);                                 \
    CVT8(lsA + ((par) << 14) + awr1, f2, f3);                                 \
  } while (0)
#define COMPUTE(par) do {                                                     \
    int pbase_ = (par) << 14;                                                 \
    bf16x8 aF[2][2], bF[2][4];                                                \
    _Pragma("unroll")                                                         \
    for (int kh = 0; kh < 2; ++kh) {                                          \
      _Pragma("unroll")                                                       \
      for (int f = 0; f < 2; ++f)                                             \
        aF[kh][f] = *(const bf16x8*)(lsA + pbase_ + ((rdA + f * 2048) ^ (kh << 6)));\
      _Pragma("unroll")                                                       \
      for (int n = 0; n < 4; ++n)                                             \
        bF[kh][n] = *(const bf16x8*)(lsB + pbase_ + ((rdB + n * 2048) ^ (kh << 6)));\
    }                                                                         \
    __builtin_amdgcn_s_setprio(1);                                            \
    _Pragma("unroll")                                                         \
    for (int kh = 0; kh < 2; ++kh)                                            \
      _Pragma("unroll")                                                       \
      for (int f = 0; f < 2; ++f)                                             \
        _Pragma("unroll")                                                     \
        for (int n = 0; n < 4; ++n)                                           \
          acc[f][n] = __builtin_amdgcn_mfma_f32_16x16x32_bf16(aF[kh][f], bF[kh][n], acc[f][n], 0, 0, 0);\
    __builtin_amdgcn_s_setprio(0);                                            \
  } while (0)
#define BARRIER do { __builtin_amdgcn_s_barrier(); asm volatile("" ::: "memory"); } while (0)

  float4 x0, x1, x2, x3, y0, y1, y2, y3;
  // prologue: queue = [tile0 (A4,B2), tile1 (A4,B2)]
  ISSUE(0, x0, x1, x2, x3);
  ISSUE(1, y0, y1, y2, y3);
  asm volatile("s_waitcnt vmcnt(6)" ::: "memory");   // tile 0 loads done
  WRITE_A(0, x0, x1, x2, x3);                        // A0 -> lsA[0]
  asm volatile("s_waitcnt lgkmcnt(0)" ::: "memory");
  BARRIER;

  for (int tt = 0; tt < 6; ++tt) {
    // even t = 2tt: compute buf0
    COMPUTE(0);
    BARRIER;                                         // buf0 reads done
    if (tt < 5) {
      ISSUE(2 * tt + 2, x0, x1, x2, x3);             // tile 2tt+2 -> x-set / lsB[0]
      asm volatile("s_waitcnt vmcnt(6)" ::: "memory");   // tile 2tt+1 done
    } else {
      asm volatile("s_waitcnt vmcnt(0)" ::: "memory");
    }
    WRITE_A(1, y0, y1, y2, y3);                      // A(2tt+1) -> lsA[1]
    asm volatile("s_waitcnt lgkmcnt(0)" ::: "memory");
    BARRIER;
    // odd t = 2tt+1: compute buf1
    COMPUTE(1);
    if (tt == 5) break;
    BARRIER;                                         // buf1 reads done
    ISSUE(2 * tt + 3, y0, y1, y2, y3);               // tile 2tt+3 -> y-set / lsB[1]
    asm volatile("s_waitcnt vmcnt(6)" ::: "memory"); // tile 2tt+2 done
    WRITE_A(0, x0, x1, x2, x3);                      // A(2tt+2) -> lsA[0]
    asm volatile("s_waitcnt lgkmcnt(0)" ::: "memory");
    BARRIER;
  }
#undef ISSUE
#undef CVT8
#undef WRITE_A
#undef COMPUTE
#undef BARRIER

  float bia[4];
#pragma unroll
  for (int n = 0; n < 4; ++n) bia[n] = bias[n0 + wn * 64 + n * 16 + lr];

  if (ntb < 6) {           // Q: * alpha^s / sqrt(d)
#pragma unroll
    for (int f = 0; f < 2; ++f)
#pragma unroll
      for (int r = 0; r < 4; ++r) {
        int mg = m0 + wm * 32 + f * 16 + lg * 4 + r;
        int b = mg >> 10, s = mg & 1023;
        float sc = exp2f((float)s * L2A) * RSQRTD;
        unsigned short* dst = Qs + ((size_t)b * SEQ + s) * DIM + n0 + wn * 64 + lr;
#pragma unroll
        for (int n = 0; n < 4; ++n)
          dst[n * 16] = f2bf((acc[f][n][r] + bia[n]) * sc);
      }
  } else if (ntb < 12) {   // K: * alpha^(-s)
#pragma unroll
    for (int f = 0; f < 2; ++f)
#pragma unroll
      for (int r = 0; r < 4; ++r) {
        int mg = m0 + wm * 32 + f * 16 + lg * 4 + r;
        int b = mg >> 10, s = mg & 1023;
        float sc = exp2f(-(float)s * L2A);
        unsigned short* dst = Ks + ((size_t)b * SEQ + s) * DIM + (n0 - DIM) + wn * 64 + lr;
#pragma unroll
        for (int n = 0; n < 4; ++n)
          dst[n * 16] = f2bf((acc[f][n][r] + bia[n]) * sc);
      }
  } else {                 // V: transpose to Vt[b][d][s]; 8B stores along s
#pragma unroll
    for (int f = 0; f < 2; ++f) {
      int mg = m0 + wm * 32 + f * 16 + lg * 4;
      int b = mg >> 10, s0 = mg & 1023;
#pragma unroll
      for (int n = 0; n < 4; ++n) {
        int d = (n0 - 2 * DIM) + wn * 64 + n * 16 + lr;
        ushort4 v;
        v.x = f2bf(acc[f][n][0] + bia[n]);
        v.y = f2bf(acc[f][n][1] + bia[n]);
        v.z = f2bf(acc[f][n][2] + bia[n]);
        v.w = f2bf(acc[f][n][3] + bia[n]);
        *(ushort4*)(Vt + ((size_t)b * DIM + d) * SEQ + s0) = v;
      }
    }
  }
}

// ---------------- scores: Sm[bl][i][j] = tril(Q' @ K'^T). 36 tril 128^2 tiles/batch
__global__ void __launch_bounds__(512, 4) score_g(
    const unsigned short* __restrict__ Qs, const unsigned short* __restrict__ Ks,
    unsigned short* __restrict__ Sm, int b_base) {
  __shared__ __align__(1024) char lsA[32768];
  __shared__ __align__(1024) char lsB[32768];
  int bid = (blockIdx.x & 7) * (gridDim.x >> 3) + (blockIdx.x >> 3);
  int t = bid % 36, bl = bid / 36;
  int b = b_base + bl;
  int it = 0;
  while (t >= it + 1) { t -= it + 1; it++; }
  int jt = t;
  int m0 = it * 128, n0 = jt * 128;
  const unsigned short* A  = Qs + (size_t)b * SEQ * DIM;
  const unsigned short* Bt = Ks + (size_t)b * SEQ * DIM;
  unsigned short* Smp = Sm + (size_t)bl * SEQ * SEQ;

  int tid = threadIdx.x, lane = tid & 63, wid = tid >> 6;
  int l8 = lane >> 3, cs = ((lane & 7) ^ l8) << 3;
  int srow = wid * 16 + l8;

  const unsigned short* gA = A  + (size_t)(m0 + srow) * DIM + cs;
  const unsigned short* gB = Bt + (size_t)(n0 + srow) * DIM + cs;

  f32x4 acc[2][4] = {};
  gemm_core(gA, gA + 8 * DIM, gB, gB + 8 * DIM, lsA, lsB, 12, wid, lane, acc);

  int wm = wid >> 1, wn = wid & 1;
  int lr = lane & 15, lg = lane >> 4;
#pragma unroll
  for (int f = 0; f < 2; ++f)
#pragma unroll
    for (int n = 0; n < 4; ++n) {
      int j = n0 + wn * 64 + n * 16 + lr;
#pragma unroll
      for (int r = 0; r < 4; ++r) {
        int i = m0 + wm * 32 + f * 16 + lg * 4 + r;
        float v = acc[f][n][r];
        if (j > i) v = 0.0f;   // causal mask (bites only on diagonal tiles)
        Smp[(size_t)i * SEQ + j] = f2bf(v);
      }
    }
}

// ---------------- PV: out[b][i][d] = Sm[bl] @ V; batch->XCD pinned, heavy-first
__global__ void __launch_bounds__(512, 4) pv_g(
    const unsigned short* __restrict__ Sm, const unsigned short* __restrict__ Vt,
    float* __restrict__ out, int b_base, int gsz) {
  __shared__ __align__(1024) char lsA[32768];
  __shared__ __align__(1024) char lsB[32768];
  int xcd = blockIdx.x & 7;
  int j = blockIdx.x >> 3;          // [0, gsz*6)
  int nbx = gsz >> 3;               // batches per XCD (1 or 2)
  int perit = nbx * 6;
  int it = 7 - j / perit;           // heavy (large kmax) first within XCD
  int rem = j % perit;
  int bl = xcd * nbx + rem / 6;
  int dt = rem % 6;
  int b = b_base + bl;
  int m0 = it * 128, n0 = dt * 128;
  const unsigned short* A  = Sm + (size_t)bl * SEQ * SEQ;   // ld 1024
  const unsigned short* Bt = Vt + (size_t)b * DIM * SEQ;    // ld 1024
  int nt = (it + 1) * 2;            // K-tiles of 64, causal bound

  int tid = threadIdx.x, lane = tid & 63, wid = tid >> 6;
  int l8 = lane >> 3, cs = ((lane & 7) ^ l8) << 3;
  int srow = wid * 16 + l8;

  const unsigned short* gA = A  + (size_t)(m0 + srow) * SEQ + cs;
  const unsigned short* gB = Bt + (size_t)(n0 + srow) * SEQ + cs;

  f32x4 acc[2][4] = {};
  gemm_core(gA, gA + 8 * SEQ, gB, gB + 8 * SEQ, lsA, lsB, nt, wid, lane, acc);

  int wm = wid >> 1, wn = wid & 1;
  int lr = lane & 15, lg = lane >> 4;
#pragma unroll
  for (int f = 0; f < 2; ++f)
#pragma unroll
    for (int n = 0; n < 4; ++n) {
      int d = n0 + wn * 64 + n * 16 + lr;
#pragma unroll
      for (int r = 0; r < 4; ++r) {
        int i = m0 + wm * 32 + f * 16 + lg * 4 + r;
        out[((size_t)b * SEQ + i) * DIM + d] = acc[f][n][r];
      }
    }
}

extern "C" void kernel_launch(void* const* d_in, const int* in_sizes, int n_in,
                              void* d_out, int out_size, void* d_ws, size_t ws_size,
                              hipStream_t stream) {
  const float* x    = (const float*)d_in[0];
  const float* W    = (const float*)d_in[1];
  const float* bias = (const float*)d_in[2];
  float* out = (float*)d_out;

  char* ws = (char*)d_ws;
  // ws: Wt 3.5MB | Qs/Ks/Vt 25.2MB each | Sm 16.8MB (8 batches) or 33.6MB (16)
  unsigned short* Wt = (unsigned short*)(ws);
  unsigned short* Qs = (unsigned short*)(ws + 3538944);
  unsigned short* Ks = (unsigned short*)(ws + 3538944 + 25165824);
  unsigned short* Vt = (unsigned short*)(ws + 3538944 + 2 * 25165824);
  unsigned short* Sm = (unsigned short*)(ws + 3538944 + 3 * 25165824);

  size_t smBase = 3538944 + 3 * (size_t)25165824;
  int gsz = (ws_size >= smBase + (size_t)16 * SEQ * SEQ * 2) ? 16 : 8;
  int ngrp = 16 / gsz;

  transpose_w<<<432, 256, 0, stream>>>(W, Wt);
  qkv_g<<<2304, 512, 0, stream>>>(x, Wt, bias, Qs, Ks, Vt);
  for (int g = 0; g < ngrp; ++g) {
    score_g<<<gsz * 36, 512, 0, stream>>>(Qs, Ks, Sm, g * gsz);
    pv_g<<<gsz * 48, 512, 0, stream>>>(Sm, Vt, out, g * gsz, gsz);
  }
}

// Round 15
// 139.241 us; speedup vs baseline: 1.1188x; 1.1188x over previous
//
#include <hip/hip_runtime.h>
#include <hip/hip_bf16.h>

// Retention: out = (tril(alpha^(i-j)) * (QK^T/sqrt(d))) @ V, qkv = x@W + b
// Decay folded into operands: Q' = q*alpha^i/sqrt(d), K' = k*alpha^(-j)
// All GEMMs: r5 core (128x128, BK=64 dbuf, 8 waves of 32x64 -> 84 regs/wave
// (52 VGPR + 32 AGPR), 64KB LDS -> 2 blocks/CU, counted vmcnt(4), 0 conflicts).
// r15 = r12 verbatim (best measured: 138.6us). qkv = r5 exact (+ushort4 V
// store); prep merged; pv batch->XCD pinned so Sm/Vt reads hit the 4MB L2.

#define SEQ   1024
#define DIM   768
#define ND3   2304

typedef __attribute__((ext_vector_type(8))) short bf16x8;
typedef __attribute__((ext_vector_type(4))) float f32x4;

#define L2A     (-0.014499569695115089f)   // log2(0.99)
#define RSQRTD  (0.03608439182435161f)     // 1/sqrt(768)

__device__ __forceinline__ unsigned short f2bf(float x) {
  union { float f; unsigned u; } v; v.f = x;
  unsigned r = v.u + 0x7FFFu + ((v.u >> 16) & 1u);
  return (unsigned short)(r >> 16);
}

__device__ __forceinline__ void gload16(const void* g, void* l) {
  __builtin_amdgcn_global_load_lds(
      (const __attribute__((address_space(1))) void*)g,
      (__attribute__((address_space(3))) void*)l, 16, 0, 0);
}

// ======================= r5 core (BK=64 dbuf, proven) =======================
// LDS per operand: 128 lines x 128B (one 64-elem K-row per line);
// line r slot b holds 16B chunk b^(r&7) [0 conflicts, measured r5/r10/r12].
__device__ __forceinline__ void gemm_core(
    const unsigned short* gA, const unsigned short* gA2,
    const unsigned short* gB, const unsigned short* gB2,
    char* lsA, char* lsB, int nt, int wid, int lane, f32x4 acc[2][4]) {
  int lr = lane & 15, lg = lane >> 4;
  int wm = wid >> 1, wn = wid & 1;
  int rdA = (wm * 32 + lr) * 128 + ((lg ^ (lr & 7)) << 4);
  int rdB = (wn * 64 + lr) * 128 + ((lg ^ (lr & 7)) << 4);
  int wo = wid * 2048;

#define STAGE(t, par) do {                                                    \
    int lo_ = ((par) << 14) + wo;                                             \
    gload16(gA  + (size_t)(t) * 64, lsA + lo_);                               \
    gload16(gA2 + (size_t)(t) * 64, lsA + lo_ + 1024);                        \
    gload16(gB  + (size_t)(t) * 64, lsB + lo_);                               \
    gload16(gB2 + (size_t)(t) * 64, lsB + lo_ + 1024);                        \
  } while (0)

  STAGE(0, 0);
  STAGE(1, 1);
  asm volatile("s_waitcnt vmcnt(4)" ::: "memory");   // tile 0 ready
  __builtin_amdgcn_s_barrier();
  asm volatile("" ::: "memory");

  for (int t = 0; t < nt; ++t) {
    int pbase = (t & 1) << 14;
    bf16x8 aF[2][2], bF[2][4];
#pragma unroll
    for (int kh = 0; kh < 2; ++kh) {
#pragma unroll
      for (int f = 0; f < 2; ++f)
        aF[kh][f] = *(const bf16x8*)(lsA + pbase + ((rdA + f * 2048) ^ (kh << 6)));
#pragma unroll
      for (int n = 0; n < 4; ++n)
        bF[kh][n] = *(const bf16x8*)(lsB + pbase + ((rdB + n * 2048) ^ (kh << 6)));
    }
    __builtin_amdgcn_s_setprio(1);
#pragma unroll
    for (int kh = 0; kh < 2; ++kh)
#pragma unroll
      for (int f = 0; f < 2; ++f)
#pragma unroll
        for (int n = 0; n < 4; ++n)
          acc[f][n] = __builtin_amdgcn_mfma_f32_16x16x32_bf16(aF[kh][f], bF[kh][n], acc[f][n], 0, 0, 0);
    __builtin_amdgcn_s_setprio(0);

    if (t == nt - 1) break;
    __builtin_amdgcn_s_barrier();            // all reads of this parity done
    asm volatile("" ::: "memory");
    if (t + 2 < nt) {
      STAGE(t + 2, t & 1);                   // refill buffer tile t used
      asm volatile("s_waitcnt vmcnt(4)" ::: "memory");   // tile t+1 ready
    } else {
      asm volatile("s_waitcnt vmcnt(0)" ::: "memory");
    }
    __builtin_amdgcn_s_barrier();
    asm volatile("" ::: "memory");
  }
#undef STAGE
}

// ---------------- prep: convert x f32->bf16 (6144 blocks) + transpose W (432)
__global__ void prep(const float* __restrict__ x, unsigned short* __restrict__ xb,
                     const float* __restrict__ W, unsigned short* __restrict__ Wt) {
  __shared__ float tile[64][65];
  int bid = blockIdx.x;
  if (bid < 6144) {               // convert_x
    size_t i = ((size_t)bid * 256 + threadIdx.x) * 8;
    float4 f0 = *(const float4*)(x + i);
    float4 f1 = *(const float4*)(x + i + 4);
    bf16x8 v;
    v[0] = (short)f2bf(f0.x); v[1] = (short)f2bf(f0.y);
    v[2] = (short)f2bf(f0.z); v[3] = (short)f2bf(f0.w);
    v[4] = (short)f2bf(f1.x); v[5] = (short)f2bf(f1.y);
    v[6] = (short)f2bf(f1.z); v[7] = (short)f2bf(f1.w);
    *(bf16x8*)(xb + i) = v;
  } else {                        // transpose_w
    int tb = bid - 6144;
    int n0 = (tb % 36) * 64;
    int k0 = (tb / 36) * 64;
    int tx = threadIdx.x & 63, ty = threadIdx.x >> 6;
#pragma unroll
    for (int p = 0; p < 16; ++p) {
      int k = ty + p * 4;
      tile[k][tx] = W[(size_t)(k0 + k) * ND3 + n0 + tx];
    }
    __syncthreads();
#pragma unroll
    for (int p = 0; p < 16; ++p) {
      int n = ty + p * 4;
      Wt[(size_t)(n0 + n) * DIM + k0 + tx] = f2bf(tile[tx][n]);
    }
  }
}

// ---------------- QKV: xb[16384][768] @ Wt^T -> Q',K',Vt. grid 2304 = 128mt x 18nt
// (r5 exact; XCD chunking gives mt in [16x, 16x+16) on XCD x -> batches 2x,2x+1)
__global__ void __launch_bounds__(512, 4) qkv_g(
    const unsigned short* __restrict__ xb, const unsigned short* __restrict__ Wt,
    const float* __restrict__ bias,
    unsigned short* __restrict__ Qs, unsigned short* __restrict__ Ks,
    unsigned short* __restrict__ Vt) {
  __shared__ __align__(1024) char lsA[32768];
  __shared__ __align__(1024) char lsB[32768];
  int bid = (blockIdx.x & 7) * 288 + (blockIdx.x >> 3);   // bijective XCD swizzle
  int mt = bid / 18, ntb = bid % 18;
  int m0 = mt * 128, n0 = ntb * 128;

  int tid = threadIdx.x, lane = tid & 63, wid = tid >> 6;
  int l8 = lane >> 3, cs = ((lane & 7) ^ l8) << 3;        // pre-swizzled chunk col
  int srow = wid * 16 + l8;

  const unsigned short* gA = xb + (size_t)(m0 + srow) * DIM + cs;
  const unsigned short* gB = Wt + (size_t)(n0 + srow) * DIM + cs;

  f32x4 acc[2][4] = {};
  gemm_core(gA, gA + 8 * DIM, gB, gB + 8 * DIM, lsA, lsB, 12, wid, lane, acc);

  int wm = wid >> 1, wn = wid & 1;
  int lr = lane & 15, lg = lane >> 4;
  float bia[4];
#pragma unroll
  for (int n = 0; n < 4; ++n) bia[n] = bias[n0 + wn * 64 + n * 16 + lr];

  if (ntb < 6) {           // Q: * alpha^s / sqrt(d)
#pragma unroll
    for (int f = 0; f < 2; ++f)
#pragma unroll
      for (int r = 0; r < 4; ++r) {
        int mg = m0 + wm * 32 + f * 16 + lg * 4 + r;
        int b = mg >> 10, s = mg & 1023;
        float sc = exp2f((float)s * L2A) * RSQRTD;
        unsigned short* dst = Qs + ((size_t)b * SEQ + s) * DIM + n0 + wn * 64 + lr;
#pragma unroll
        for (int n = 0; n < 4; ++n)
          dst[n * 16] = f2bf((acc[f][n][r] + bia[n]) * sc);
      }
  } else if (ntb < 12) {   // K: * alpha^(-s)
#pragma unroll
    for (int f = 0; f < 2; ++f)
#pragma unroll
      for (int r = 0; r < 4; ++r) {
        int mg = m0 + wm * 32 + f * 16 + lg * 4 + r;
        int b = mg >> 10, s = mg & 1023;
        float sc = exp2f(-(float)s * L2A);
        unsigned short* dst = Ks + ((size_t)b * SEQ + s) * DIM + (n0 - DIM) + wn * 64 + lr;
#pragma unroll
        for (int n = 0; n < 4; ++n)
          dst[n * 16] = f2bf((acc[f][n][r] + bia[n]) * sc);
      }
  } else {                 // V: transpose to Vt[b][d][s]; r runs along s -> 8B stores
#pragma unroll
    for (int f = 0; f < 2; ++f) {
      int mg = m0 + wm * 32 + f * 16 + lg * 4;
      int b = mg >> 10, s0 = mg & 1023;
#pragma unroll
      for (int n = 0; n < 4; ++n) {
        int d = (n0 - 2 * DIM) + wn * 64 + n * 16 + lr;
        ushort4 v;
        v.x = f2bf(acc[f][n][0] + bia[n]);
        v.y = f2bf(acc[f][n][1] + bia[n]);
        v.z = f2bf(acc[f][n][2] + bia[n]);
        v.w = f2bf(acc[f][n][3] + bia[n]);
        *(ushort4*)(Vt + ((size_t)b * DIM + d) * SEQ + s0) = v;
      }
    }
  }
}

// ---------------- scores: Sm[bl][i][j] = tril(Q' @ K'^T). 36 tril 128^2 tiles/batch
__global__ void __launch_bounds__(512, 4) score_g(
    const unsigned short* __restrict__ Qs, const unsigned short* __restrict__ Ks,
    unsigned short* __restrict__ Sm, int b_base) {
  __shared__ __align__(1024) char lsA[32768];
  __shared__ __align__(1024) char lsB[32768];
  int bid = (blockIdx.x & 7) * (gridDim.x >> 3) + (blockIdx.x >> 3);
  int t = bid % 36, bl = bid / 36;
  int b = b_base + bl;
  int it = 0;
  while (t >= it + 1) { t -= it + 1; it++; }
  int jt = t;
  int m0 = it * 128, n0 = jt * 128;
  const unsigned short* A  = Qs + (size_t)b * SEQ * DIM;
  const unsigned short* Bt = Ks + (size_t)b * SEQ * DIM;
  unsigned short* Smp = Sm + (size_t)bl * SEQ * SEQ;

  int tid = threadIdx.x, lane = tid & 63, wid = tid >> 6;
  int l8 = lane >> 3, cs = ((lane & 7) ^ l8) << 3;
  int srow = wid * 16 + l8;

  const unsigned short* gA = A  + (size_t)(m0 + srow) * DIM + cs;
  const unsigned short* gB = Bt + (size_t)(n0 + srow) * DIM + cs;

  f32x4 acc[2][4] = {};
  gemm_core(gA, gA + 8 * DIM, gB, gB + 8 * DIM, lsA, lsB, 12, wid, lane, acc);

  int wm = wid >> 1, wn = wid & 1;
  int lr = lane & 15, lg = lane >> 4;
#pragma unroll
  for (int f = 0; f < 2; ++f)
#pragma unroll
    for (int n = 0; n < 4; ++n) {
      int j = n0 + wn * 64 + n * 16 + lr;
#pragma unroll
      for (int r = 0; r < 4; ++r) {
        int i = m0 + wm * 32 + f * 16 + lg * 4 + r;
        float v = acc[f][n][r];
        if (j > i) v = 0.0f;   // causal mask (bites only on diagonal tiles)
        Smp[(size_t)i * SEQ + j] = f2bf(v);
      }
    }
}

// ---------------- PV: out[b][i][d] = Sm[bl] @ V; batch->XCD pinned, heavy-first
// XCD x owns batches [x*(gsz/8), (x+1)*(gsz/8)); within an XCD, it descends.
// Sm(b) (2MB) and Vt(b) (1.6MB) were written on the same XCD -> L2 hits.
__global__ void __launch_bounds__(512, 4) pv_g(
    const unsigned short* __restrict__ Sm, const unsigned short* __restrict__ Vt,
    float* __restrict__ out, int b_base, int gsz) {
  __shared__ __align__(1024) char lsA[32768];
  __shared__ __align__(1024) char lsB[32768];
  int xcd = blockIdx.x & 7;
  int j = blockIdx.x >> 3;          // [0, gsz*6)
  int nbx = gsz >> 3;               // batches per XCD (1 or 2)
  int perit = nbx * 6;
  int it = 7 - j / perit;           // heavy (large kmax) first within XCD
  int rem = j % perit;
  int bl = xcd * nbx + rem / 6;
  int dt = rem % 6;
  int b = b_base + bl;
  int m0 = it * 128, n0 = dt * 128;
  const unsigned short* A  = Sm + (size_t)bl * SEQ * SEQ;   // ld 1024
  const unsigned short* Bt = Vt + (size_t)b * DIM * SEQ;    // ld 1024
  int nt = (it + 1) * 2;            // K-tiles of 64, causal bound

  int tid = threadIdx.x, lane = tid & 63, wid = tid >> 6;
  int l8 = lane >> 3, cs = ((lane & 7) ^ l8) << 3;
  int srow = wid * 16 + l8;

  const unsigned short* gA = A  + (size_t)(m0 + srow) * SEQ + cs;
  const unsigned short* gB = Bt + (size_t)(n0 + srow) * SEQ + cs;

  f32x4 acc[2][4] = {};
  gemm_core(gA, gA + 8 * SEQ, gB, gB + 8 * SEQ, lsA, lsB, nt, wid, lane, acc);

  int wm = wid >> 1, wn = wid & 1;
  int lr = lane & 15, lg = lane >> 4;
#pragma unroll
  for (int f = 0; f < 2; ++f)
#pragma unroll
    for (int n = 0; n < 4; ++n) {
      int d = n0 + wn * 64 + n * 16 + lr;
#pragma unroll
      for (int r = 0; r < 4; ++r) {
        int i = m0 + wm * 32 + f * 16 + lg * 4 + r;
        out[((size_t)b * SEQ + i) * DIM + d] = acc[f][n][r];
      }
    }
}

extern "C" void kernel_launch(void* const* d_in, const int* in_sizes, int n_in,
                              void* d_out, int out_size, void* d_ws, size_t ws_size,
                              hipStream_t stream) {
  const float* x    = (const float*)d_in[0];
  const float* W    = (const float*)d_in[1];
  const float* bias = (const float*)d_in[2];
  float* out = (float*)d_out;

  char* ws = (char*)d_ws;
  // ws: Wt 3.5MB | Qs/Ks/Vt 25.2MB each | Sm 16.8MB (8 batches) or 33.6MB (16)
  unsigned short* Wt = (unsigned short*)(ws);
  unsigned short* Qs = (unsigned short*)(ws + 3538944);
  unsigned short* Ks = (unsigned short*)(ws + 3538944 + 25165824);
  unsigned short* Vt = (unsigned short*)(ws + 3538944 + 2 * 25165824);
  unsigned short* Sm = (unsigned short*)(ws + 3538944 + 3 * 25165824);
  // bf16 x lives in d_out (50.3MB >= 25.2MB); fully consumed by qkv before pv writes.
  unsigned short* xb = (unsigned short*)d_out;

  size_t smBase = 3538944 + 3 * (size_t)25165824;
  int gsz = (ws_size >= smBase + (size_t)16 * SEQ * SEQ * 2) ? 16 : 8;
  int ngrp = 16 / gsz;

  prep<<<6576, 256, 0, stream>>>(x, xb, W, Wt);
  qkv_g<<<2304, 512, 0, stream>>>(xb, Wt, bias, Qs, Ks, Vt);
  for (int g = 0; g < ngrp; ++g) {
    score_g<<<gsz * 36, 512, 0, stream>>>(Qs, Ks, Sm, g * gsz);
    pv_g<<<gsz * 48, 512, 0, stream>>>(Sm, Vt, out, g * gsz, gsz);
  }
}